// Round 8
// baseline (231.374 us; speedup 1.0000x reference)
//
#include <hip/hip_runtime.h>
#include <math.h>

// ConvBertLightConv: dynamic depthwise conv with softmax-normalized per-(pos,head) kernels.
// B=8, S=4096, D=768 (12 heads x 64), K=9, 'same' zero padding along S.
// out[b,s,h,d] = sum_k softmax(filters[b,s,h,:])[k] * x[b, s+k-4, h*64+d]
//
// R10 = R9 with the compile fix: __builtin_nontemporal_store requires a NATIVE
// vector type, not HIP's float4 class -> use ext_vector_type(4) throughout.
//
// R9 theory (unchanged): clone the m13 copy-kernel shape. Pooled R3/R7/R8 + m13
// evidence: loaded-chip per-wave BW is ~0.6-1.1 GB/s universally (the 6.29 TB/s
// copy = 0.77/wave at ~32 waves/CU); BW = waves x in-flight/latency. Maximize
// resident waves AND per-wave duty; eliminate everything that idles a wave:
//  - NO LDS, NO barriers, NO per-block setup phases.
//  - wave owns 16 consecutive rows x 64 float4 cols (s wave-uniform -> scalar guards).
//  - per iteration: 9 INDEPENDENT window loads issued first (9 KB/wave in flight),
//    then filter taps (vmcnt completes in-order: waiting for taps => x landed),
//    per-lane softmax (VALU 84% idle, redundancy free), FMA, non-temporal store
//    (out is write-once; keep L3 for x+filt).
//  - 1536 blocks x 256 thr = 6144 waves, ALL co-resident (6 blocks/CU, zero churn,
//    uniform lifetime). launch_bounds(256,8) pins VGPR<=64 (est ~59) -> 24 waves/CU.
//  - blockIdx = G*24 + bc, stride 24 == 0 mod 8: s-adjacent strips land on the SAME
//    XCD -> window re-reads (8/9 overlap) are L2-local; L3 (185 MB < 256 MB) absorbs
//    the rest, HBM fetch stays ~1x.

#define KS 9
#define HD 64
#define NH 12
#define DMODEL 768              // NH*HD
#define SEQ 4096
#define BATCH 8
#define FSTRIDE (NH * KS)       // 108
#define L 16                    // rows per wave
#define WPB 4                   // waves per block (256 threads)
#define NTHREADS 256
#define NGROUPS (SEQ / (L * WPB))   // 64 row-groups
#define NBC (BATCH * 3)             // 24 (batch x col-chunk)
#define NBLOCKS (NGROUPS * NBC)     // 1536 = 6 blocks/CU, all co-resident

typedef float f32x4 __attribute__((ext_vector_type(4)));

__global__ __launch_bounds__(NTHREADS, 8) void lightconv_kernel(
    const float* __restrict__ x,      // [B, S, 768]
    const float* __restrict__ filt,   // [B, S, 108]
    float* __restrict__ out)          // [B, S, 768]
{
    const int bid  = blockIdx.x;
    const int G    = bid / NBC;            // slow index: stride-24 neighbors (same XCD)
    const int bc   = bid % NBC;
    const int b    = bc / 3;               // batch 0..7
    const int c    = bc % 3;               // col-chunk 0..2 (64 float4 each)
    const int wav  = threadIdx.x >> 6;     // 0..3
    const int lane = threadIdx.x & 63;

    const int s0   = (G * WPB + wav) * L;  // wave's first output row
    const int col4 = c * 64 + lane;        // float4 column 0..191
    const int head = col4 >> 4;            // 0..11

    const float* xc = x    + (size_t)b * SEQ * DMODEL + col4 * 4;
    float*       oc = out  + (size_t)b * SEQ * DMODEL + col4 * 4;
    const float* fc = filt + (size_t)b * SEQ * FSTRIDE + head * KS;

    const f32x4 zero = (f32x4)(0.f);

#pragma unroll 1                           // keep regs <=64: no cross-iter pipeline
    for (int i = 0; i < L; ++i) {
        const int s = s0 + i;

        // 9 independent window loads; guard is wave-uniform (s uniform in wave)
        f32x4 win[KS];
#pragma unroll
        for (int k = 0; k < KS; ++k) {
            const int ss = s + k - (KS / 2);
            win[k] = ((unsigned)ss < (unsigned)SEQ)
                   ? *reinterpret_cast<const f32x4*>(xc + (size_t)ss * DMODEL)
                   : zero;
        }

        // filter taps: issued after x -> in-order vmcnt drain covers x too.
        // 16 lanes of a head read the same 36 B (one request), L1/L2-served.
        const float* fp = fc + (size_t)s * FSTRIDE;
        float w[KS];
        float m = -1e30f;
#pragma unroll
        for (int k = 0; k < KS; ++k) { w[k] = fp[k]; m = fmaxf(m, w[k]); }
        float sum = 0.f;
#pragma unroll
        for (int k = 0; k < KS; ++k) { w[k] = __expf(w[k] - m); sum += w[k]; }
        const float inv = 1.0f / sum;

        f32x4 acc = zero;
#pragma unroll
        for (int k = 0; k < KS; ++k) {
            acc += (w[k] * inv) * win[k];
        }
        // write-once output: non-temporal store keeps L3 for x + filters
        __builtin_nontemporal_store(acc, reinterpret_cast<f32x4*>(oc + (size_t)s * DMODEL));
    }
}

extern "C" void kernel_launch(void* const* d_in, const int* in_sizes, int n_in,
                              void* d_out, int out_size, void* d_ws, size_t ws_size,
                              hipStream_t stream) {
    const float* x    = (const float*)d_in[0];   // [8,4096,768] fp32
    const float* filt = (const float*)d_in[1];   // [8,4096,108] fp32
    float* out        = (float*)d_out;           // [8,4096,12,64] fp32

    lightconv_kernel<<<NBLOCKS, NTHREADS, 0, stream>>>(x, filt, out);
}